// Round 5
// baseline (347.548 us; speedup 1.0000x reference)
//
#include <hip/hip_runtime.h>

constexpr int B = 16, N = 128, D = 128, DN0 = 64, DE0 = 16;

typedef _Float16 half8 __attribute__((ext_vector_type(8)));
typedef _Float16 half4 __attribute__((ext_vector_type(4)));
typedef float floatx4 __attribute__((ext_vector_type(4)));

// async 16B global->LDS (per-lane gsrc, wave-uniform lds base; HW scatters
// lane L's 16B to ldsbase + L*16). msg0/T2 global layout is cell-swizzled
// (16B cell g of row j stored at g^(j&15)) so the linear copy lands
// conflict-free in LDS.
__device__ __forceinline__ void gld16(const _Float16* g, _Float16* l) {
  __builtin_amdgcn_global_load_lds(
      (const __attribute__((address_space(1))) void*)g,
      (__attribute__((address_space(3))) void*)l, 16, 0, 0);
}

// ---------------------------------------------------------------------------
// K0: WeT prep. WeT_l[c][k] = (fp16) w_msg_l[2D+k][c], layers 1 and 2.
// ---------------------------------------------------------------------------
__global__ __launch_bounds__(128) void k_wprep(
    const float* __restrict__ wm1, const float* __restrict__ wm2,
    _Float16* __restrict__ weT1, _Float16* __restrict__ weT2) {
  const int bid = blockIdx.x;            // 256 blocks
  const int layer = bid >> 7, c = bid & 127;
  const int k = threadIdx.x;
  const float* src = layer ? wm2 : wm1;
  _Float16* dst = layer ? weT2 : weT1;
  dst[c * D + k] = (_Float16)src[(2 * D + k) * D + c];
}

// ---------------------------------------------------------------------------
// K1: xi0 = x @ Wi0 + b_msg0 ; xj0 = x @ Wj0      (2048 blocks)
// ---------------------------------------------------------------------------
__global__ __launch_bounds__(128) void k_pre0(
    const float* __restrict__ x, const float* __restrict__ wm0,
    const float* __restrict__ bm0,
    float* __restrict__ xi0, float* __restrict__ xj0) {
  const int row = blockIdx.x;
  const int c = threadIdx.x;
  __shared__ float xr[DN0];
  if (c < DN0) xr[c] = x[row * DN0 + c];
  __syncthreads();
  float ai = bm0[c], aj = 0.f;
  #pragma unroll 8
  for (int k = 0; k < DN0; ++k) {
    const float xv = xr[k];
    ai = fmaf(xv, wm0[k * D + c], ai);
    aj = fmaf(xv, wm0[(DN0 + k) * D + c], aj);
  }
  xi0[row * D + c] = ai;
  xj0[row * D + c] = aj;
}

// ---------------------------------------------------------------------------
// K2: layer-0 edge kernel (K=16, VALU fp32). msg0 stored fp16 with the
// cell-swizzled row layout (cell (c>>3)^(j&15)).
// ---------------------------------------------------------------------------
__global__ __launch_bounds__(256) void k_edge0(
    const int* __restrict__ ei, const float* __restrict__ eattr,
    const float* __restrict__ wm0,
    const float* __restrict__ xi0, const float* __restrict__ xj0,
    _Float16* __restrict__ msg0, float* __restrict__ agg0) {
  const int row = blockIdx.x;
  const int b = row >> 7;
  const int t = threadIdx.x;
  const int c4 = (t & 31) * 4, jb = t >> 5;

  __shared__ float e_row[N][20];
  __shared__ float w_t[DE0][D];
  __shared__ float amask[N];
  __shared__ float xi_r[D];
  __shared__ float hp2[8][32][4];

  const float4* esrc = (const float4*)(eattr + (size_t)row * N * DE0);
  const float4* wsrc = (const float4*)(wm0 + 2 * DN0 * D);
  #pragma unroll
  for (int u = 0; u < 2; ++u) {
    const int idx4 = u * 256 + t;
    const int j = idx4 >> 2;
    const int k4 = (idx4 & 3) * 4;
    *(float4*)&e_row[j][k4] = esrc[idx4];
    ((float4*)&w_t[0][0])[idx4] = wsrc[idx4];
  }
  if (t < N) {
    amask[t] = (float)ei[(size_t)row * N + t];
    xi_r[t] = xi0[row * D + t];
  }
  __syncthreads();

  float acc[16][4] = {};
  #pragma unroll 4
  for (int k = 0; k < DE0; ++k) {
    float av[16];
    #pragma unroll
    for (int p = 0; p < 16; ++p) av[p] = e_row[jb + 8 * p][k];
    const floatx4 wv = *(const floatx4*)&w_t[k][c4];
    #pragma unroll
    for (int p = 0; p < 16; ++p)
      #pragma unroll
      for (int q = 0; q < 4; ++q)
        acc[p][q] = fmaf(av[p], wv[q], acc[p][q]);
  }

  float hq[4] = {};
  const float* xjb = xj0 + (size_t)b * N * D;
  _Float16* mrow = msg0 + (size_t)row * N * D;
  const floatx4 xiv = *(const floatx4*)&xi_r[c4];
  #pragma unroll
  for (int p = 0; p < 16; ++p) {
    const int j = jb + 8 * p;
    const float am = amask[j];
    const floatx4 xjv = *(const floatx4*)&xjb[j * D + c4];
    half4 hv;
    #pragma unroll
    for (int q = 0; q < 4; ++q) {
      float v = xiv[q] + xjv[q] + acc[p][q];
      v = fmaxf(v, 0.f) * am;
      hv[q] = (_Float16)v;
      hq[q] += v;
    }
    const int cell = (c4 >> 3) ^ (j & 15);           // swizzled global layout
    *(half4*)&mrow[j * D + cell * 8 + (c4 & 7)] = hv;
  }
  #pragma unroll
  for (int q = 0; q < 4; ++q) hp2[jb][t & 31][q] = hq[q];
  __syncthreads();
  if (t < D) {
    float s = 0.f;
    #pragma unroll
    for (int g = 0; g < 8; ++g) s += hp2[g][t >> 2][t & 3];
    agg0[row * D + t] = s;
  }
}

// ---------------------------------------------------------------------------
// K3: node update 0 + xi1/xj1 precompute.
// ---------------------------------------------------------------------------
__global__ __launch_bounds__(128) void k_node0(
    const float* __restrict__ x0, const float* __restrict__ agg0,
    const float* __restrict__ wn0, const float* __restrict__ bn0,
    const float* __restrict__ wm1, const float* __restrict__ bm1,
    float* __restrict__ x1, float* __restrict__ xi1, float* __restrict__ xj1) {
  const int row = blockIdx.x;
  const int c = threadIdx.x;
  __shared__ float xr[DN0], ar[D], x1r[D];
  if (c < DN0) xr[c] = x0[row * DN0 + c];
  ar[c] = agg0[row * D + c];
  __syncthreads();
  float a = bn0[c];
  #pragma unroll 8
  for (int k = 0; k < DN0; ++k) a = fmaf(xr[k], wn0[k * D + c], a);
  #pragma unroll 8
  for (int k = 0; k < D; ++k) a = fmaf(ar[k], wn0[(DN0 + k) * D + c], a);
  a = fmaxf(a, 0.f);
  x1[row * D + c] = a;
  x1r[c] = a;
  __syncthreads();
  float ai = bm1[c], aj = 0.f;
  #pragma unroll 8
  for (int k = 0; k < D; ++k) {
    const float xv = x1r[k];
    ai = fmaf(xv, wm1[k * D + c], ai);
    aj = fmaf(xv, wm1[(D + k) * D + c], aj);
  }
  xi1[row * D + c] = ai;
  xj1[row * D + c] = aj;
}

// K5: node update 1; agg1 arrives as 4 per-wave partials from k_mid.
__global__ __launch_bounds__(128) void k_node1(
    const float* __restrict__ x1, const float* __restrict__ agg1p,
    const float* __restrict__ wn1, const float* __restrict__ bn1,
    const float* __restrict__ wm2, const float* __restrict__ bm2,
    float* __restrict__ xi2, float* __restrict__ xj2) {
  const int row = blockIdx.x;
  const int c = threadIdx.x;
  __shared__ float x1r[D], ar[D], x2r[D];
  x1r[c] = x1[row * D + c];
  float a0 = 0.f;
  #pragma unroll
  for (int w = 0; w < 4; ++w) a0 += agg1p[((size_t)row * 4 + w) * D + c];
  ar[c] = a0;
  __syncthreads();
  float a = bn1[c];
  #pragma unroll 8
  for (int k = 0; k < D; ++k) a = fmaf(x1r[k], wn1[k * D + c], a);
  #pragma unroll 8
  for (int k = 0; k < D; ++k) a = fmaf(ar[k], wn1[(D + k) * D + c], a);
  x2r[c] = 0.5f * (x1r[c] + fmaxf(a, 0.f));
  __syncthreads();
  float ai = bm2[c], aj = 0.f;
  #pragma unroll 8
  for (int k = 0; k < D; ++k) {
    const float xv = x2r[k];
    ai = fmaf(xv, wm2[k * D + c], ai);
    aj = fmaf(xv, wm2[(D + k) * D + c], aj);
  }
  xi2[row * D + c] = ai;
  xj2[row * D + c] = aj;
}

// ---------------------------------------------------------------------------
// K4: fused layer-1+2 edge kernel, multi-row pipelined.
// 512 blocks (b=blk>>5, 4 rows each), 2 blocks/CU (64 KB LDS exactly).
// Per block: We1T/We2T frags in regs (loaded once), xj1[b] staged to LDS fp16
// once. Per (row, half=64 j): async global_load_lds staging, double-buffered;
// prefetch issued post-barrier so it streams under the current half's MFMA.
// Each wave owns 16 j-rows per half end-to-end (stage/MFMA/RMW/deposit/
// copy-out) -> no intra-loop cross-wave traffic. agg1 out as 4 wave partials.
// ---------------------------------------------------------------------------
__global__ __launch_bounds__(256, 2) void k_mid(
    const int* __restrict__ ei, const _Float16* __restrict__ weT1,
    const _Float16* __restrict__ weT2,
    const float* __restrict__ xi, const float* __restrict__ xj,
    _Float16* __restrict__ em,          // in: msg0 (swizzled), out: T2
    float* __restrict__ agg1p) {
  const int blk = blockIdx.x;           // 512
  const int b = blk >> 5, g = blk & 31;
  const int row0 = b * 128 + g * 4;
  const int t = threadIdx.x;
  const int w = t >> 6, lane = t & 63;
  const int lm = lane & 15, lq = lane >> 4;

  __shared__ _Float16 sE[2][64 * 128];  // 2 x 16 KB half-row staging
  __shared__ _Float16 sXj[128 * 128];   // 32 KB xj1[b] fp16, cell-swizzled

  // --- weight fragments in registers, once per block (L2-hot) ---
  half8 a1[8][4], a2[8][4];
  #pragma unroll
  for (int ct = 0; ct < 8; ++ct)
    #pragma unroll
    for (int ks = 0; ks < 4; ++ks) {
      a1[ct][ks] = *(const half8*)(weT1 + (16 * ct + lm) * D + 8 * lq + 32 * ks);
      a2[ct][ks] = *(const half8*)(weT2 + (16 * ct + lm) * D + 8 * lq + 32 * ks);
    }

  // --- prefetch idx 0 (row0, half 0): wave w stages its 16 rows (4 KB) ---
  {
    const _Float16* gsrc = em + (size_t)row0 * N * D + (16 * w) * D + lane * 8;
    _Float16* lbase = &sE[0][(16 * w) * D];
    #pragma unroll
    for (int i = 0; i < 4; ++i) gld16(gsrc + i * 512, lbase + i * 512);
  }

  // --- stage xj[b] -> LDS fp16, cell-swizzled ---
  {
    const float4* xjb4 = (const float4*)(xj + (size_t)b * N * D);
    #pragma unroll
    for (int u = 0; u < 16; ++u) {
      const int idx4 = u * 256 + t;     // 0..4095
      const int j = idx4 >> 5;
      const int c4 = (idx4 & 31) * 4;
      const float4 v = xjb4[idx4];
      half4 hv;
      hv[0] = (_Float16)v.x; hv[1] = (_Float16)v.y;
      hv[2] = (_Float16)v.z; hv[3] = (_Float16)v.w;
      const int cell = (c4 >> 3) ^ (j & 15);
      *(half4*)&sXj[j * D + cell * 8 + (c4 & 7)] = hv;
    }
  }

  floatx4 xiv[8];
  floatx4 hacc[8];

  for (int idx = 0; idx < 8; ++idx) {
    const int ridx = idx >> 1, h = idx & 1;
    const int row = row0 + ridx;
    __syncthreads();                     // drains prefetch(idx) + prior stores

    // prefetch idx+1 into the other buffer; streams under this half's compute
    if (idx < 7) {
      const int nr = (idx + 1) >> 1, nh = (idx + 1) & 1;
      const _Float16* gsrc = em + (size_t)(row0 + nr) * N * D +
                             (64 * nh + 16 * w) * D + lane * 8;
      _Float16* lbase = &sE[(idx + 1) & 1][(16 * w) * D];
      #pragma unroll
      for (int i = 0; i < 4; ++i) gld16(gsrc + i * 512, lbase + i * 512);
    }

    if (h == 0) {
      #pragma unroll
      for (int ct = 0; ct < 8; ++ct) {
        xiv[ct] = *(const floatx4*)&xi[(size_t)row * D + 16 * ct + 4 * lq];
        hacc[ct] = (floatx4){0.f, 0.f, 0.f, 0.f};
      }
    }

    const int j = 64 * h + 16 * w + lm;  // j&15 == lm
    const int jl = 16 * w + lm;          // row within staging buffer
    const float am = (float)ei[(size_t)row * N + j];
    _Float16* buf = sE[idx & 1];

    // --- pass 1: T1 = We1T x msg0 ---
    floatx4 acc[8];
    #pragma unroll
    for (int ct = 0; ct < 8; ++ct) acc[ct] = (floatx4){0.f, 0.f, 0.f, 0.f};
    #pragma unroll
    for (int ks = 0; ks < 4; ++ks) {
      const half8 bv = *(const half8*)&buf[jl * D + (((lq + 4 * ks) ^ lm) * 8)];
      #pragma unroll
      for (int ct = 0; ct < 8; ++ct)
        acc[ct] = __builtin_amdgcn_mfma_f32_16x16x32_f16(a1[ct][ks], bv, acc[ct], 0, 0, 0);
    }

    // --- epilogue: msg1, hacc, e_mid RMW in place ---
    #pragma unroll
    for (int ct = 0; ct < 8; ++ct) {
      const int off = (((2 * ct + (lq >> 1)) ^ lm) << 3) + 4 * (lq & 1);
      const half4 m0 = *(const half4*)&buf[jl * D + off];
      const half4 xjv = *(const half4*)&sXj[j * D + off];
      half4 mid;
      floatx4 m1;
      #pragma unroll
      for (int r = 0; r < 4; ++r) {
        const float v = xiv[ct][r] + (float)xjv[r] + acc[ct][r];
        m1[r] = fmaxf(v, 0.f) * am;
        mid[r] = (_Float16)(0.5f * ((float)m0[r] + m1[r]));
      }
      *(half4*)&buf[jl * D + off] = mid;  // own row
      hacc[ct] += m1;
    }

    // --- pass 2: T2 = We2T x e_mid ---
    #pragma unroll
    for (int ct = 0; ct < 8; ++ct) acc[ct] = (floatx4){0.f, 0.f, 0.f, 0.f};
    #pragma unroll
    for (int ks = 0; ks < 4; ++ks) {
      const half8 bv = *(const half8*)&buf[jl * D + (((lq + 4 * ks) ^ lm) * 8)];
      #pragma unroll
      for (int ct = 0; ct < 8; ++ct)
        acc[ct] = __builtin_amdgcn_mfma_f32_16x16x32_f16(a2[ct][ks], bv, acc[ct], 0, 0, 0);
    }

    // --- deposit T2 into buffer (own rows), then coalesced copy-out ---
    #pragma unroll
    for (int ct = 0; ct < 8; ++ct) {
      const int off = (((2 * ct + (lq >> 1)) ^ lm) << 3) + 4 * (lq & 1);
      half4 tv;
      #pragma unroll
      for (int r = 0; r < 4; ++r) tv[r] = (_Float16)acc[ct][r];
      *(half4*)&buf[jl * D + off] = tv;
    }
    {
      _Float16* gdst = em + (size_t)row * N * D + (64 * h + 16 * w) * D + lane * 8;
      const _Float16* lsrc = &buf[(16 * w) * D] + lane * 8;
      #pragma unroll
      for (int i = 0; i < 4; ++i)
        *(uint4*)(gdst + i * 512) = *(const uint4*)(lsrc + i * 512);
    }

    // --- per-wave agg partial after second half ---
    if (h == 1) {
      #pragma unroll
      for (int m = 1; m < 16; m <<= 1)
        #pragma unroll
        for (int ct = 0; ct < 8; ++ct)
          #pragma unroll
          for (int r = 0; r < 4; ++r)
            hacc[ct][r] += __shfl_xor(hacc[ct][r], m, 64);
      if (lm == 0) {
        #pragma unroll
        for (int ct = 0; ct < 8; ++ct)
          *(floatx4*)&agg1p[((size_t)row * 4 + w) * D + 16 * ct + 4 * lq] = hacc[ct];
      }
    }
  }
}

// ---------------------------------------------------------------------------
// K6: final layer streaming: msg2 = relu(xi2 + xj2 + T2)*A; rowsum over j.
// T2 rows are cell-swizzled.
// ---------------------------------------------------------------------------
__global__ __launch_bounds__(256) void k_fin(
    const int* __restrict__ ei, const _Float16* __restrict__ t2,
    const float* __restrict__ xi, const float* __restrict__ xj,
    float* __restrict__ rowsum) {
  const int row = blockIdx.x;
  const int b = row >> 7;
  const int t = threadIdx.x;
  const int c8 = (t & 15) * 8, jr = t >> 4;

  __shared__ float sMask[N];
  __shared__ float hp[16][16][8];
  if (t < N) sMask[t] = (float)ei[(size_t)row * N + t];
  float xiv[8];
  *(floatx4*)&xiv[0] = *(const floatx4*)&xi[row * D + c8];
  *(floatx4*)&xiv[4] = *(const floatx4*)&xi[row * D + c8 + 4];
  __syncthreads();

  const _Float16* src = t2 + (size_t)row * N * D;
  const float* xjb = xj + (size_t)b * N * D;
  float acc8[8] = {};
  #pragma unroll
  for (int u = 0; u < 8; ++u) {
    const int j = u * 16 + jr;           // j&15 == jr
    const half8 tv = *(const half8*)(src + j * D + (((t & 15) ^ jr) << 3));
    const float am = sMask[j];
    const floatx4 xj0 = *(const floatx4*)&xjb[j * D + c8];
    const floatx4 xj1 = *(const floatx4*)&xjb[j * D + c8 + 4];
    #pragma unroll
    for (int r = 0; r < 4; ++r) {
      acc8[r]     += fmaxf(xiv[r] + xj0[r] + (float)tv[r], 0.f) * am;
      acc8[4 + r] += fmaxf(xiv[4 + r] + xj1[r] + (float)tv[4 + r], 0.f) * am;
    }
  }
  #pragma unroll
  for (int k = 0; k < 8; ++k) hp[jr][t & 15][k] = acc8[k];
  __syncthreads();
  if (t < D) {
    float s = 0.f;
    #pragma unroll
    for (int g = 0; g < 16; ++g) s += hp[g][t >> 3][t & 7];
    rowsum[row * D + t] = s;
  }
}

// ---------------------------------------------------------------------------
// K7: head MLP. 16 blocks.
// ---------------------------------------------------------------------------
__global__ __launch_bounds__(128) void k_head(
    const float* __restrict__ rowsum,
    const float* __restrict__ w1, const float* __restrict__ b1,
    const float* __restrict__ w2, const float* __restrict__ b2,
    const float* __restrict__ w3, const float* __restrict__ b3,
    float* __restrict__ out) {
  const int b = blockIdx.x;
  const int c = threadIdx.x;
  __shared__ float hr[D], h1r[D], h2r[D];
  const float* rs = rowsum + (size_t)b * N * D;
  float s = 0.f;
  for (int i = 0; i < N; ++i) s += rs[i * D + c];
  hr[c] = s * (1.f / (N * N));
  __syncthreads();
  float a = b1[c];
  #pragma unroll 8
  for (int k = 0; k < D; ++k) a = fmaf(hr[k], w1[k * D + c], a);
  h1r[c] = fmaxf(a, 0.f);
  __syncthreads();
  a = b2[c];
  #pragma unroll 8
  for (int k = 0; k < D; ++k) a = fmaf(h1r[k], w2[k * D + c], a);
  h2r[c] = fmaxf(a, 0.f);
  __syncthreads();
  hr[c] = h2r[c] * w3[c];
  __syncthreads();
  if (c == 0) {
    float s2 = b3[0];
    for (int k = 0; k < D; ++k) s2 += hr[k];
    out[b] = s2;
  }
}

// ---------------------------------------------------------------------------
extern "C" void kernel_launch(void* const* d_in, const int* in_sizes, int n_in,
                              void* d_out, int out_size, void* d_ws, size_t ws_size,
                              hipStream_t stream) {
  const int*   ei  = (const int*)d_in[0];
  const float* x0  = (const float*)d_in[1];
  const float* ea  = (const float*)d_in[2];
  const float* wm0 = (const float*)d_in[3];
  const float* bm0 = (const float*)d_in[4];
  const float* wn0 = (const float*)d_in[5];
  const float* bn0 = (const float*)d_in[6];
  const float* wm1 = (const float*)d_in[7];
  const float* bm1 = (const float*)d_in[8];
  const float* wn1 = (const float*)d_in[9];
  const float* bn1 = (const float*)d_in[10];
  const float* wm2 = (const float*)d_in[11];
  const float* bm2 = (const float*)d_in[12];
  const float* wh1 = (const float*)d_in[15];
  const float* bh1 = (const float*)d_in[16];
  const float* wh2 = (const float*)d_in[17];
  const float* bh2 = (const float*)d_in[18];
  const float* wh3 = (const float*)d_in[19];
  const float* bh3 = (const float*)d_in[20];
  float* out = (float*)d_out;

  _Float16* msg0h = (_Float16*)d_ws;                 // [B,N,N,D] fp16: msg0 -> T2
  _Float16* weT1  = msg0h + (size_t)B * N * N * D;
  _Float16* weT2  = weT1 + D * D;
  float* f = (float*)(weT2 + D * D);
  size_t off = 0;
  const size_t R = (size_t)B * N * D;
  float* xi0   = f + off; off += R;
  float* xj0   = f + off; off += R;
  float* agg0  = f + off; off += R;
  float* x1    = f + off; off += R;
  float* xi1   = f + off; off += R;
  float* xj1   = f + off; off += R;
  float* agg1p = f + off; off += 4 * R;              // 4 per-wave partials
  float* xi2   = f + off; off += R;
  float* xj2   = f + off; off += R;
  float* rsum  = f + off; off += R;

  const int rows = B * N;   // 2048
  k_wprep<<<256, 128, 0, stream>>>(wm1, wm2, weT1, weT2);
  k_pre0 <<<rows, 128, 0, stream>>>(x0, wm0, bm0, xi0, xj0);
  k_edge0<<<rows, 256, 0, stream>>>(ei, ea, wm0, xi0, xj0, msg0h, agg0);
  k_node0<<<rows, 128, 0, stream>>>(x0, agg0, wn0, bn0, wm1, bm1, x1, xi1, xj1);
  k_mid  <<<512,  256, 0, stream>>>(ei, weT1, weT2, xi1, xj1, msg0h, agg1p);
  k_node1<<<rows, 128, 0, stream>>>(x1, agg1p, wn1, bn1, wm2, bm2, xi2, xj2);
  k_fin  <<<rows, 256, 0, stream>>>(ei, msg0h, xi2, xj2, rsum);
  k_head <<<B,    128, 0, stream>>>(rsum, wh1, bh1, wh2, bh2, wh3, bh3, out);
}

// Round 6
// 240.673 us; speedup vs baseline: 1.4441x; 1.4441x over previous
//
#include <hip/hip_runtime.h>

constexpr int B = 16, N = 128, D = 128, DN0 = 64, DE0 = 16;

typedef _Float16 half8 __attribute__((ext_vector_type(8)));
typedef _Float16 half4 __attribute__((ext_vector_type(4)));
typedef float floatx4 __attribute__((ext_vector_type(4)));

// async 16B global->LDS (per-lane gsrc, wave-uniform lds base; HW scatters
// lane L's 16B to ldsbase + L*16). msg0/T2 global layout is cell-swizzled
// (16B cell g of row j stored at g^(j&15)) so the linear copy lands
// conflict-free in LDS.
__device__ __forceinline__ void gld16(const _Float16* g, _Float16* l) {
  __builtin_amdgcn_global_load_lds(
      (const __attribute__((address_space(1))) void*)g,
      (__attribute__((address_space(3))) void*)l, 16, 0, 0);
}

// ---------------------------------------------------------------------------
// K0: WeT prep. WeT_l[c][k] = (fp16) w_msg_l[2D+k][c], layers 1 and 2.
// ---------------------------------------------------------------------------
__global__ __launch_bounds__(128) void k_wprep(
    const float* __restrict__ wm1, const float* __restrict__ wm2,
    _Float16* __restrict__ weT1, _Float16* __restrict__ weT2) {
  const int bid = blockIdx.x;            // 256 blocks
  const int layer = bid >> 7, c = bid & 127;
  const int k = threadIdx.x;
  const float* src = layer ? wm2 : wm1;
  _Float16* dst = layer ? weT2 : weT1;
  dst[c * D + k] = (_Float16)src[(2 * D + k) * D + c];
}

// ---------------------------------------------------------------------------
// K1: xi0 = x @ Wi0 + b_msg0 ; xj0 = x @ Wj0      (2048 blocks)
// ---------------------------------------------------------------------------
__global__ __launch_bounds__(128) void k_pre0(
    const float* __restrict__ x, const float* __restrict__ wm0,
    const float* __restrict__ bm0,
    float* __restrict__ xi0, float* __restrict__ xj0) {
  const int row = blockIdx.x;
  const int c = threadIdx.x;
  __shared__ float xr[DN0];
  if (c < DN0) xr[c] = x[row * DN0 + c];
  __syncthreads();
  float ai = bm0[c], aj = 0.f;
  #pragma unroll 8
  for (int k = 0; k < DN0; ++k) {
    const float xv = xr[k];
    ai = fmaf(xv, wm0[k * D + c], ai);
    aj = fmaf(xv, wm0[(DN0 + k) * D + c], aj);
  }
  xi0[row * D + c] = ai;
  xj0[row * D + c] = aj;
}

// ---------------------------------------------------------------------------
// K2: layer-0 edge kernel (K=16, VALU fp32). msg0 stored fp16 with the
// cell-swizzled row layout (cell (c>>3)^(j&15)).
// ---------------------------------------------------------------------------
__global__ __launch_bounds__(256) void k_edge0(
    const int* __restrict__ ei, const float* __restrict__ eattr,
    const float* __restrict__ wm0,
    const float* __restrict__ xi0, const float* __restrict__ xj0,
    _Float16* __restrict__ msg0, float* __restrict__ agg0) {
  const int row = blockIdx.x;
  const int b = row >> 7;
  const int t = threadIdx.x;
  const int c4 = (t & 31) * 4, jb = t >> 5;

  __shared__ float e_row[N][20];
  __shared__ float w_t[DE0][D];
  __shared__ float amask[N];
  __shared__ float xi_r[D];
  __shared__ float hp2[8][32][4];

  const float4* esrc = (const float4*)(eattr + (size_t)row * N * DE0);
  const float4* wsrc = (const float4*)(wm0 + 2 * DN0 * D);
  #pragma unroll
  for (int u = 0; u < 2; ++u) {
    const int idx4 = u * 256 + t;
    const int j = idx4 >> 2;
    const int k4 = (idx4 & 3) * 4;
    *(float4*)&e_row[j][k4] = esrc[idx4];
    ((float4*)&w_t[0][0])[idx4] = wsrc[idx4];
  }
  if (t < N) {
    amask[t] = (float)ei[(size_t)row * N + t];
    xi_r[t] = xi0[row * D + t];
  }
  __syncthreads();

  float acc[16][4] = {};
  #pragma unroll 4
  for (int k = 0; k < DE0; ++k) {
    float av[16];
    #pragma unroll
    for (int p = 0; p < 16; ++p) av[p] = e_row[jb + 8 * p][k];
    const floatx4 wv = *(const floatx4*)&w_t[k][c4];
    #pragma unroll
    for (int p = 0; p < 16; ++p)
      #pragma unroll
      for (int q = 0; q < 4; ++q)
        acc[p][q] = fmaf(av[p], wv[q], acc[p][q]);
  }

  float hq[4] = {};
  const float* xjb = xj0 + (size_t)b * N * D;
  _Float16* mrow = msg0 + (size_t)row * N * D;
  const floatx4 xiv = *(const floatx4*)&xi_r[c4];
  #pragma unroll
  for (int p = 0; p < 16; ++p) {
    const int j = jb + 8 * p;
    const float am = amask[j];
    const floatx4 xjv = *(const floatx4*)&xjb[j * D + c4];
    half4 hv;
    #pragma unroll
    for (int q = 0; q < 4; ++q) {
      float v = xiv[q] + xjv[q] + acc[p][q];
      v = fmaxf(v, 0.f) * am;
      hv[q] = (_Float16)v;
      hq[q] += v;
    }
    const int cell = (c4 >> 3) ^ (j & 15);           // swizzled global layout
    *(half4*)&mrow[j * D + cell * 8 + (c4 & 7)] = hv;
  }
  #pragma unroll
  for (int q = 0; q < 4; ++q) hp2[jb][t & 31][q] = hq[q];
  __syncthreads();
  if (t < D) {
    float s = 0.f;
    #pragma unroll
    for (int g = 0; g < 8; ++g) s += hp2[g][t >> 2][t & 3];
    agg0[row * D + t] = s;
  }
}

// ---------------------------------------------------------------------------
// K3: node update 0 + xi1/xj1 precompute.
// ---------------------------------------------------------------------------
__global__ __launch_bounds__(128) void k_node0(
    const float* __restrict__ x0, const float* __restrict__ agg0,
    const float* __restrict__ wn0, const float* __restrict__ bn0,
    const float* __restrict__ wm1, const float* __restrict__ bm1,
    float* __restrict__ x1, float* __restrict__ xi1, float* __restrict__ xj1) {
  const int row = blockIdx.x;
  const int c = threadIdx.x;
  __shared__ float xr[DN0], ar[D], x1r[D];
  if (c < DN0) xr[c] = x0[row * DN0 + c];
  ar[c] = agg0[row * D + c];
  __syncthreads();
  float a = bn0[c];
  #pragma unroll 8
  for (int k = 0; k < DN0; ++k) a = fmaf(xr[k], wn0[k * D + c], a);
  #pragma unroll 8
  for (int k = 0; k < D; ++k) a = fmaf(ar[k], wn0[(DN0 + k) * D + c], a);
  a = fmaxf(a, 0.f);
  x1[row * D + c] = a;
  x1r[c] = a;
  __syncthreads();
  float ai = bm1[c], aj = 0.f;
  #pragma unroll 8
  for (int k = 0; k < D; ++k) {
    const float xv = x1r[k];
    ai = fmaf(xv, wm1[k * D + c], ai);
    aj = fmaf(xv, wm1[(D + k) * D + c], aj);
  }
  xi1[row * D + c] = ai;
  xj1[row * D + c] = aj;
}

// K5: node update 1 (agg1 is a plain [rows,D] array again).
__global__ __launch_bounds__(128) void k_node1(
    const float* __restrict__ x1, const float* __restrict__ agg1,
    const float* __restrict__ wn1, const float* __restrict__ bn1,
    const float* __restrict__ wm2, const float* __restrict__ bm2,
    float* __restrict__ xi2, float* __restrict__ xj2) {
  const int row = blockIdx.x;
  const int c = threadIdx.x;
  __shared__ float x1r[D], ar[D], x2r[D];
  x1r[c] = x1[row * D + c];
  ar[c] = agg1[row * D + c];
  __syncthreads();
  float a = bn1[c];
  #pragma unroll 8
  for (int k = 0; k < D; ++k) a = fmaf(x1r[k], wn1[k * D + c], a);
  #pragma unroll 8
  for (int k = 0; k < D; ++k) a = fmaf(ar[k], wn1[(D + k) * D + c], a);
  x2r[c] = 0.5f * (x1r[c] + fmaxf(a, 0.f));
  __syncthreads();
  float ai = bm2[c], aj = 0.f;
  #pragma unroll 8
  for (int k = 0; k < D; ++k) {
    const float xv = x2r[k];
    ai = fmaf(xv, wm2[k * D + c], ai);
    aj = fmaf(xv, wm2[(D + k) * D + c], aj);
  }
  xi2[row * D + c] = ai;
  xj2[row * D + c] = aj;
}

// ---------------------------------------------------------------------------
// K4: fused layer-1+2 edge kernel. One block per (b,i) row, 512 thr = 8 waves.
// Wave w owns channel tile c in [16w,16w+16) for ALL 128 j (c-split, not
// j-split): per-wave weights = a1[4]+a2[4] = 32 VGPRs (j-split needed 256 ->
// R5 spill). Each wave reads the whole 32 KB tile per pass from LDS; LDS-pipe
// floor ~4096 cyc/row. agg1 completes per-wave (shuffle over lm spans all j).
// Phases per row: stage -> P1 MFMA -> RMW(e_mid) -> P2 MFMA -> deposit(T2)
// -> copy-out, barrier-separated; staging latency hidden by co-resident block.
// ---------------------------------------------------------------------------
__global__ __launch_bounds__(512, 4) void k_mid(
    const int* __restrict__ ei, const _Float16* __restrict__ weT1,
    const _Float16* __restrict__ weT2,
    const float* __restrict__ xi, const float* __restrict__ xj,
    _Float16* __restrict__ em,          // in: msg0 (swizzled), out: T2
    float* __restrict__ agg1) {
  const int row = blockIdx.x;           // 2048
  const int b = row >> 7;
  const int t = threadIdx.x;
  const int w = t >> 6;                 // ct = w
  const int lane = t & 63;
  const int lm = lane & 15, lq = lane >> 4;

  __shared__ _Float16 sE[N * D];        // 32 KB, swizzled rows

  // weight frags for this wave's c-tile (32 VGPRs total both layers)
  half8 a1[4];
  #pragma unroll
  for (int ks = 0; ks < 4; ++ks)
    a1[ks] = *(const half8*)(weT1 + (16 * w + lm) * D + 8 * lq + 32 * ks);

  // async-stage msg0 row: linear copy of the swizzled layout (conflict-free)
  const _Float16* gsrc = em + (size_t)row * N * D;
  #pragma unroll
  for (int u = 0; u < 4; ++u) {
    const int seg = (u * 8 + w) * 512;  // halves; wave-uniform base
    gld16(gsrc + seg + lane * 8, &sE[seg]);
  }

  // per-lane row data (overlap with staging)
  const int c0 = 16 * w + 4 * lq;
  const floatx4 xiv = *(const floatx4*)&xi[(size_t)row * D + c0];
  float am[8];
  #pragma unroll
  for (int jt = 0; jt < 8; ++jt)
    am[jt] = (float)ei[(size_t)row * N + 16 * jt + lm];

  __syncthreads();                      // drains gld16

  // --- pass 1: T1[c][j] = sum_k We1T[c][k] msg0[j][k] ---
  floatx4 acc[8];
  #pragma unroll
  for (int jt = 0; jt < 8; ++jt) acc[jt] = (floatx4){0.f, 0.f, 0.f, 0.f};
  #pragma unroll
  for (int ks = 0; ks < 4; ++ks)
    #pragma unroll
    for (int jt = 0; jt < 8; ++jt) {
      const half8 bv = *(const half8*)&sE[(16 * jt + lm) * D + (((lq + 4 * ks) ^ lm) << 3)];
      acc[jt] = __builtin_amdgcn_mfma_f32_16x16x32_f16(a1[ks], bv, acc[jt], 0, 0, 0);
    }

  __syncthreads();                      // all pass-1 reads complete

  // --- epilogue 1: msg1 -> agg, e_mid RMW in LDS ---
  const float* xjb = xj + (size_t)b * N * D;
  floatx4 hacc = (floatx4){0.f, 0.f, 0.f, 0.f};
  #pragma unroll
  for (int jt = 0; jt < 8; ++jt) {
    const int j = 16 * jt + lm;         // j & 15 == lm
    const int hidx = j * D + (((2 * w + (lq >> 1)) ^ lm) << 3) + 4 * (lq & 1);
    const floatx4 xjv = *(const floatx4*)&xjb[j * D + c0];
    const half4 m0 = *(const half4*)&sE[hidx];
    half4 mid;
    floatx4 m1;
    #pragma unroll
    for (int r = 0; r < 4; ++r) {
      const float v = xiv[r] + xjv[r] + acc[jt][r];
      m1[r] = fmaxf(v, 0.f) * am[jt];
      mid[r] = (_Float16)(0.5f * ((float)m0[r] + m1[r]));
    }
    *(half4*)&sE[hidx] = mid;
    hacc += m1;
  }

  // load pass-2 weights here (latency overlaps the barrier + first ds_reads)
  half8 a2[4];
  #pragma unroll
  for (int ks = 0; ks < 4; ++ks)
    a2[ks] = *(const half8*)(weT2 + (16 * w + lm) * D + 8 * lq + 32 * ks);

  __syncthreads();                      // e_mid visible to all waves

  // --- pass 2: T2[c][j] = sum_k We2T[c][k] e_mid[j][k] ---
  #pragma unroll
  for (int jt = 0; jt < 8; ++jt) acc[jt] = (floatx4){0.f, 0.f, 0.f, 0.f};
  #pragma unroll
  for (int ks = 0; ks < 4; ++ks)
    #pragma unroll
    for (int jt = 0; jt < 8; ++jt) {
      const half8 bv = *(const half8*)&sE[(16 * jt + lm) * D + (((lq + 4 * ks) ^ lm) << 3)];
      acc[jt] = __builtin_amdgcn_mfma_f32_16x16x32_f16(a2[ks], bv, acc[jt], 0, 0, 0);
    }

  // agg1: butterfly over lm spans all 128 j for this wave's 4 c
  #pragma unroll
  for (int m = 1; m < 16; m <<= 1)
    #pragma unroll
    for (int r = 0; r < 4; ++r)
      hacc[r] += __shfl_xor(hacc[r], m, 64);
  if (lm == 0)
    *(floatx4*)&agg1[(size_t)row * D + c0] = hacc;

  __syncthreads();                      // all pass-2 reads complete

  // --- deposit T2 into sE (same cell mapping) ---
  #pragma unroll
  for (int jt = 0; jt < 8; ++jt) {
    const int j = 16 * jt + lm;
    const int hidx = j * D + (((2 * w + (lq >> 1)) ^ lm) << 3) + 4 * (lq & 1);
    half4 tv;
    #pragma unroll
    for (int r = 0; r < 4; ++r) tv[r] = (_Float16)acc[jt][r];
    *(half4*)&sE[hidx] = tv;
  }

  __syncthreads();                      // T2 complete in LDS

  // --- coalesced copy-out (keeps swizzled global layout) ---
  uint4* gdst = (uint4*)(em + (size_t)row * N * D);
  const uint4* ls = (const uint4*)sE;
  #pragma unroll
  for (int u = 0; u < 4; ++u) {
    const int idx4 = (u * 8 + w) * 64 + lane;
    gdst[idx4] = ls[idx4];
  }
}

// ---------------------------------------------------------------------------
// K6: final layer streaming: msg2 = relu(xi2 + xj2 + T2)*A; rowsum over j.
// T2 rows are cell-swizzled.
// ---------------------------------------------------------------------------
__global__ __launch_bounds__(256) void k_fin(
    const int* __restrict__ ei, const _Float16* __restrict__ t2,
    const float* __restrict__ xi, const float* __restrict__ xj,
    float* __restrict__ rowsum) {
  const int row = blockIdx.x;
  const int b = row >> 7;
  const int t = threadIdx.x;
  const int c8 = (t & 15) * 8, jr = t >> 4;

  __shared__ float sMask[N];
  __shared__ float hp[16][16][8];
  if (t < N) sMask[t] = (float)ei[(size_t)row * N + t];
  float xiv[8];
  *(floatx4*)&xiv[0] = *(const floatx4*)&xi[row * D + c8];
  *(floatx4*)&xiv[4] = *(const floatx4*)&xi[row * D + c8 + 4];
  __syncthreads();

  const _Float16* src = t2 + (size_t)row * N * D;
  const float* xjb = xj + (size_t)b * N * D;
  float acc8[8] = {};
  #pragma unroll
  for (int u = 0; u < 8; ++u) {
    const int j = u * 16 + jr;           // j&15 == jr
    const half8 tv = *(const half8*)(src + j * D + (((t & 15) ^ jr) << 3));
    const float am = sMask[j];
    const floatx4 xj0 = *(const floatx4*)&xjb[j * D + c8];
    const floatx4 xj1 = *(const floatx4*)&xjb[j * D + c8 + 4];
    #pragma unroll
    for (int r = 0; r < 4; ++r) {
      acc8[r]     += fmaxf(xiv[r] + xj0[r] + (float)tv[r], 0.f) * am;
      acc8[4 + r] += fmaxf(xiv[4 + r] + xj1[r] + (float)tv[4 + r], 0.f) * am;
    }
  }
  #pragma unroll
  for (int k = 0; k < 8; ++k) hp[jr][t & 15][k] = acc8[k];
  __syncthreads();
  if (t < D) {
    float s = 0.f;
    #pragma unroll
    for (int g = 0; g < 16; ++g) s += hp[g][t >> 3][t & 7];
    rowsum[row * D + t] = s;
  }
}

// ---------------------------------------------------------------------------
// K7: head MLP. 16 blocks.
// ---------------------------------------------------------------------------
__global__ __launch_bounds__(128) void k_head(
    const float* __restrict__ rowsum,
    const float* __restrict__ w1, const float* __restrict__ b1,
    const float* __restrict__ w2, const float* __restrict__ b2,
    const float* __restrict__ w3, const float* __restrict__ b3,
    float* __restrict__ out) {
  const int b = blockIdx.x;
  const int c = threadIdx.x;
  __shared__ float hr[D], h1r[D], h2r[D];
  const float* rs = rowsum + (size_t)b * N * D;
  float s = 0.f;
  for (int i = 0; i < N; ++i) s += rs[i * D + c];
  hr[c] = s * (1.f / (N * N));
  __syncthreads();
  float a = b1[c];
  #pragma unroll 8
  for (int k = 0; k < D; ++k) a = fmaf(hr[k], w1[k * D + c], a);
  h1r[c] = fmaxf(a, 0.f);
  __syncthreads();
  a = b2[c];
  #pragma unroll 8
  for (int k = 0; k < D; ++k) a = fmaf(h1r[k], w2[k * D + c], a);
  h2r[c] = fmaxf(a, 0.f);
  __syncthreads();
  hr[c] = h2r[c] * w3[c];
  __syncthreads();
  if (c == 0) {
    float s2 = b3[0];
    for (int k = 0; k < D; ++k) s2 += hr[k];
    out[b] = s2;
  }
}

// ---------------------------------------------------------------------------
extern "C" void kernel_launch(void* const* d_in, const int* in_sizes, int n_in,
                              void* d_out, int out_size, void* d_ws, size_t ws_size,
                              hipStream_t stream) {
  const int*   ei  = (const int*)d_in[0];
  const float* x0  = (const float*)d_in[1];
  const float* ea  = (const float*)d_in[2];
  const float* wm0 = (const float*)d_in[3];
  const float* bm0 = (const float*)d_in[4];
  const float* wn0 = (const float*)d_in[5];
  const float* bn0 = (const float*)d_in[6];
  const float* wm1 = (const float*)d_in[7];
  const float* bm1 = (const float*)d_in[8];
  const float* wn1 = (const float*)d_in[9];
  const float* bn1 = (const float*)d_in[10];
  const float* wm2 = (const float*)d_in[11];
  const float* bm2 = (const float*)d_in[12];
  const float* wh1 = (const float*)d_in[15];
  const float* bh1 = (const float*)d_in[16];
  const float* wh2 = (const float*)d_in[17];
  const float* bh2 = (const float*)d_in[18];
  const float* wh3 = (const float*)d_in[19];
  const float* bh3 = (const float*)d_in[20];
  float* out = (float*)d_out;

  _Float16* msg0h = (_Float16*)d_ws;                 // [B,N,N,D] fp16: msg0 -> T2
  _Float16* weT1  = msg0h + (size_t)B * N * N * D;
  _Float16* weT2  = weT1 + D * D;
  float* f = (float*)(weT2 + D * D);
  size_t off = 0;
  const size_t R = (size_t)B * N * D;
  float* xi0  = f + off; off += R;
  float* xj0  = f + off; off += R;
  float* agg0 = f + off; off += R;
  float* x1   = f + off; off += R;
  float* xi1  = f + off; off += R;
  float* xj1  = f + off; off += R;
  float* agg1 = f + off; off += R;
  float* xi2  = f + off; off += R;
  float* xj2  = f + off; off += R;
  float* rsum = f + off; off += R;

  const int rows = B * N;   // 2048
  k_wprep<<<256, 128, 0, stream>>>(wm1, wm2, weT1, weT2);
  k_pre0 <<<rows, 128, 0, stream>>>(x0, wm0, bm0, xi0, xj0);
  k_edge0<<<rows, 256, 0, stream>>>(ei, ea, wm0, xi0, xj0, msg0h, agg0);
  k_node0<<<rows, 128, 0, stream>>>(x0, agg0, wn0, bn0, wm1, bm1, x1, xi1, xj1);
  k_mid  <<<rows, 512, 0, stream>>>(ei, weT1, weT2, xi1, xj1, msg0h, agg1);
  k_node1<<<rows, 128, 0, stream>>>(x1, agg1, wn1, bn1, wm2, bm2, xi2, xj2);
  k_fin  <<<rows, 256, 0, stream>>>(ei, msg0h, xi2, xj2, rsum);
  k_head <<<B,    128, 0, stream>>>(rsum, wh1, bh1, wh2, bh2, wh3, bh3, out);
}

// Round 8
// 239.374 us; speedup vs baseline: 1.4519x; 1.0054x over previous
//
#include <hip/hip_runtime.h>

constexpr int B = 16, N = 128, D = 128, DN0 = 64, DE0 = 16;

typedef _Float16 half8 __attribute__((ext_vector_type(8)));
typedef _Float16 half4 __attribute__((ext_vector_type(4)));
typedef float floatx4 __attribute__((ext_vector_type(4)));
typedef float floatx16 __attribute__((ext_vector_type(16)));

// async 16B global->LDS (per-lane gsrc, wave-uniform lds base; HW scatters
// lane L's 16B to ldsbase + L*16). msg0/T2 global layout is cell-swizzled
// (16B cell g of row j stored at g^(j&15)) so the linear copy lands
// conflict-free in LDS.
__device__ __forceinline__ void gld16(const _Float16* g, _Float16* l) {
  __builtin_amdgcn_global_load_lds(
      (const __attribute__((address_space(1))) void*)g,
      (__attribute__((address_space(3))) void*)l, 16, 0, 0);
}

// ---------------------------------------------------------------------------
// K0: WeT prep. WeT_l[c][k] = (fp16) w_msg_l[2D+k][c], layers 1 and 2.
// ---------------------------------------------------------------------------
__global__ __launch_bounds__(128) void k_wprep(
    const float* __restrict__ wm1, const float* __restrict__ wm2,
    _Float16* __restrict__ weT1, _Float16* __restrict__ weT2) {
  const int bid = blockIdx.x;            // 256 blocks
  const int layer = bid >> 7, c = bid & 127;
  const int k = threadIdx.x;
  const float* src = layer ? wm2 : wm1;
  _Float16* dst = layer ? weT2 : weT1;
  dst[c * D + k] = (_Float16)src[(2 * D + k) * D + c];
}

// ---------------------------------------------------------------------------
// K1: xi0 = x @ Wi0 + b_msg0 ; xj0 = x @ Wj0      (2048 blocks)
// ---------------------------------------------------------------------------
__global__ __launch_bounds__(128) void k_pre0(
    const float* __restrict__ x, const float* __restrict__ wm0,
    const float* __restrict__ bm0,
    float* __restrict__ xi0, float* __restrict__ xj0) {
  const int row = blockIdx.x;
  const int c = threadIdx.x;
  __shared__ float xr[DN0];
  if (c < DN0) xr[c] = x[row * DN0 + c];
  __syncthreads();
  float ai = bm0[c], aj = 0.f;
  #pragma unroll 8
  for (int k = 0; k < DN0; ++k) {
    const float xv = xr[k];
    ai = fmaf(xv, wm0[k * D + c], ai);
    aj = fmaf(xv, wm0[(DN0 + k) * D + c], aj);
  }
  xi0[row * D + c] = ai;
  xj0[row * D + c] = aj;
}

// ---------------------------------------------------------------------------
// K2: layer-0 edge kernel (K=16, VALU fp32). msg0 stored fp16 with the
// cell-swizzled row layout (cell (c>>3)^(j&15)).
// ---------------------------------------------------------------------------
__global__ __launch_bounds__(256) void k_edge0(
    const int* __restrict__ ei, const float* __restrict__ eattr,
    const float* __restrict__ wm0,
    const float* __restrict__ xi0, const float* __restrict__ xj0,
    _Float16* __restrict__ msg0, float* __restrict__ agg0) {
  const int row = blockIdx.x;
  const int b = row >> 7;
  const int t = threadIdx.x;
  const int c4 = (t & 31) * 4, jb = t >> 5;

  __shared__ float e_row[N][20];
  __shared__ float w_t[DE0][D];
  __shared__ float amask[N];
  __shared__ float xi_r[D];
  __shared__ float hp2[8][32][4];

  const float4* esrc = (const float4*)(eattr + (size_t)row * N * DE0);
  const float4* wsrc = (const float4*)(wm0 + 2 * DN0 * D);
  #pragma unroll
  for (int u = 0; u < 2; ++u) {
    const int idx4 = u * 256 + t;
    const int j = idx4 >> 2;
    const int k4 = (idx4 & 3) * 4;
    *(float4*)&e_row[j][k4] = esrc[idx4];
    ((float4*)&w_t[0][0])[idx4] = wsrc[idx4];
  }
  if (t < N) {
    amask[t] = (float)ei[(size_t)row * N + t];
    xi_r[t] = xi0[row * D + t];
  }
  __syncthreads();

  float acc[16][4] = {};
  #pragma unroll 4
  for (int k = 0; k < DE0; ++k) {
    float av[16];
    #pragma unroll
    for (int p = 0; p < 16; ++p) av[p] = e_row[jb + 8 * p][k];
    const floatx4 wv = *(const floatx4*)&w_t[k][c4];
    #pragma unroll
    for (int p = 0; p < 16; ++p)
      #pragma unroll
      for (int q = 0; q < 4; ++q)
        acc[p][q] = fmaf(av[p], wv[q], acc[p][q]);
  }

  float hq[4] = {};
  const float* xjb = xj0 + (size_t)b * N * D;
  _Float16* mrow = msg0 + (size_t)row * N * D;
  const floatx4 xiv = *(const floatx4*)&xi_r[c4];
  #pragma unroll
  for (int p = 0; p < 16; ++p) {
    const int j = jb + 8 * p;
    const float am = amask[j];
    const floatx4 xjv = *(const floatx4*)&xjb[j * D + c4];
    half4 hv;
    #pragma unroll
    for (int q = 0; q < 4; ++q) {
      float v = xiv[q] + xjv[q] + acc[p][q];
      v = fmaxf(v, 0.f) * am;
      hv[q] = (_Float16)v;
      hq[q] += v;
    }
    const int cell = (c4 >> 3) ^ (j & 15);           // swizzled global layout
    *(half4*)&mrow[j * D + cell * 8 + (c4 & 7)] = hv;
  }
  #pragma unroll
  for (int q = 0; q < 4; ++q) hp2[jb][t & 31][q] = hq[q];
  __syncthreads();
  if (t < D) {
    float s = 0.f;
    #pragma unroll
    for (int g = 0; g < 8; ++g) s += hp2[g][t >> 2][t & 3];
    agg0[row * D + t] = s;
  }
}

// ---------------------------------------------------------------------------
// K3: node update 0 + xi1/xj1 precompute.
// ---------------------------------------------------------------------------
__global__ __launch_bounds__(128) void k_node0(
    const float* __restrict__ x0, const float* __restrict__ agg0,
    const float* __restrict__ wn0, const float* __restrict__ bn0,
    const float* __restrict__ wm1, const float* __restrict__ bm1,
    float* __restrict__ x1, float* __restrict__ xi1, float* __restrict__ xj1) {
  const int row = blockIdx.x;
  const int c = threadIdx.x;
  __shared__ float xr[DN0], ar[D], x1r[D];
  if (c < DN0) xr[c] = x0[row * DN0 + c];
  ar[c] = agg0[row * D + c];
  __syncthreads();
  float a = bn0[c];
  #pragma unroll 8
  for (int k = 0; k < DN0; ++k) a = fmaf(xr[k], wn0[k * D + c], a);
  #pragma unroll 8
  for (int k = 0; k < D; ++k) a = fmaf(ar[k], wn0[(DN0 + k) * D + c], a);
  a = fmaxf(a, 0.f);
  x1[row * D + c] = a;
  x1r[c] = a;
  __syncthreads();
  float ai = bm1[c], aj = 0.f;
  #pragma unroll 8
  for (int k = 0; k < D; ++k) {
    const float xv = x1r[k];
    ai = fmaf(xv, wm1[k * D + c], ai);
    aj = fmaf(xv, wm1[(D + k) * D + c], aj);
  }
  xi1[row * D + c] = ai;
  xj1[row * D + c] = aj;
}

// K5: node update 1.
__global__ __launch_bounds__(128) void k_node1(
    const float* __restrict__ x1, const float* __restrict__ agg1,
    const float* __restrict__ wn1, const float* __restrict__ bn1,
    const float* __restrict__ wm2, const float* __restrict__ bm2,
    float* __restrict__ xi2, float* __restrict__ xj2) {
  const int row = blockIdx.x;
  const int c = threadIdx.x;
  __shared__ float x1r[D], ar[D], x2r[D];
  x1r[c] = x1[row * D + c];
  ar[c] = agg1[row * D + c];
  __syncthreads();
  float a = bn1[c];
  #pragma unroll 8
  for (int k = 0; k < D; ++k) a = fmaf(x1r[k], wn1[k * D + c], a);
  #pragma unroll 8
  for (int k = 0; k < D; ++k) a = fmaf(ar[k], wn1[(D + k) * D + c], a);
  x2r[c] = 0.5f * (x1r[c] + fmaxf(a, 0.f));
  __syncthreads();
  float ai = bm2[c], aj = 0.f;
  #pragma unroll 8
  for (int k = 0; k < D; ++k) {
    const float xv = x2r[k];
    ai = fmaf(xv, wm2[k * D + c], ai);
    aj = fmaf(xv, wm2[(D + k) * D + c], aj);
  }
  xi2[row * D + c] = ai;
  xj2[row * D + c] = aj;
}

// ---------------------------------------------------------------------------
// K4: fused layer-1+2 edge kernel. One block per (b,i) row, 256 thr = 4 waves.
// mfma_f32_32x32x16_f16: wave w owns c-tile [32w,32w+32), all 128 j.
// R7 bug fixed: copy-out loop ran u<16 (4096 uint4 = 64 KB) over a 2048-uint4
// (32 KB) row -> clobbered row+1's T2 with OOB-LDS garbage. Now u<8.
// C/D layout (m74/m101 + AMD lab notes): col(j)=lane&31,
// row(c)=(reg&3)+8*(reg>>2)+4*(lane>>5). A/B k-layout uncertainty self-cancels
// (same lane-consistent bijection on both operands).
// ---------------------------------------------------------------------------
__global__ __launch_bounds__(256, 2) void k_mid(
    const int* __restrict__ ei, const _Float16* __restrict__ weT1,
    const _Float16* __restrict__ weT2,
    const float* __restrict__ xi, const float* __restrict__ xj,
    _Float16* __restrict__ em,          // in: msg0 (swizzled), out: T2
    float* __restrict__ agg1) {
  const int row = blockIdx.x;           // 2048
  const int b = row >> 7;
  const int t = threadIdx.x;
  const int w = t >> 6;                 // c-tile base 32w
  const int lane = t & 63;
  const int l31 = lane & 31;
  const int l15 = lane & 15;
  const int hl = lane >> 5;             // k-half; c offset 4*hl

  __shared__ _Float16 sE[N * D];        // 32 KB, swizzled rows

  // --- async-stage msg0 row (linear copy of swizzled layout) ---
  const _Float16* gsrc = em + (size_t)row * N * D;
  #pragma unroll
  for (int u = 0; u < 8; ++u) {
    const int seg = (u * 4 + w) * 512;  // wave-uniform base, 1 KB per instr
    gld16(gsrc + seg + lane * 8, &sE[seg]);
  }

  // --- pass-1 weight frags: A[m=l31][k=16ks+8hl+e] ---
  half8 a1[8];
  #pragma unroll
  for (int ks = 0; ks < 8; ++ks)
    a1[ks] = *(const half8*)(weT1 + (32 * w + l31) * D + 16 * ks + 8 * hl);

  // --- per-lane invariants (overlap staging) ---
  floatx4 xiv[4];
  #pragma unroll
  for (int g = 0; g < 4; ++g)
    xiv[g] = *(const floatx4*)&xi[(size_t)row * D + 32 * w + 8 * g + 4 * hl];
  float am[4];
  #pragma unroll
  for (int jt = 0; jt < 4; ++jt)
    am[jt] = (float)ei[(size_t)row * N + 32 * jt + l31];

  __syncthreads();                      // drains gld16

  // --- pass 1: T1[c][j] = sum_k We1T[c][k] msg0[j][k] ---
  const floatx16 vzero = {0.f,0.f,0.f,0.f,0.f,0.f,0.f,0.f,
                          0.f,0.f,0.f,0.f,0.f,0.f,0.f,0.f};
  floatx16 acc[4];
  #pragma unroll
  for (int jt = 0; jt < 4; ++jt) acc[jt] = vzero;
  #pragma unroll
  for (int ks = 0; ks < 8; ++ks)
    #pragma unroll
    for (int jt = 0; jt < 4; ++jt) {
      const half8 bv = *(const half8*)
          &sE[(32 * jt + l31) * D + (((2 * ks + hl) ^ l15) << 3)];
      acc[jt] = __builtin_amdgcn_mfma_f32_32x32x16_f16(a1[ks], bv, acc[jt], 0, 0, 0);
    }

  __syncthreads();                      // all pass-1 reads complete

  // --- epilogue 1: msg1 -> hacc, e_mid RMW in LDS ---
  const float* xjb = xj + (size_t)b * N * D;
  floatx4 hacc[4];
  #pragma unroll
  for (int g = 0; g < 4; ++g) hacc[g] = (floatx4){0.f, 0.f, 0.f, 0.f};
  #pragma unroll
  for (int jt = 0; jt < 4; ++jt) {
    const int j = 32 * jt + l31;        // j&15 == l15
    #pragma unroll
    for (int g = 0; g < 4; ++g) {
      const int cofs = 32 * w + 8 * g + 4 * hl;
      const int hidx = j * D + (((4 * w + g) ^ l15) << 3) + 4 * hl;
      const floatx4 xjv = *(const floatx4*)&xjb[j * D + cofs];
      const half4 m0 = *(const half4*)&sE[hidx];
      half4 mid;
      floatx4 m1;
      #pragma unroll
      for (int r = 0; r < 4; ++r) {
        const float v = xiv[g][r] + xjv[r] + acc[jt][4 * g + r];
        m1[r] = fmaxf(v, 0.f) * am[jt];
        mid[r] = (_Float16)(0.5f * ((float)m0[r] + m1[r]));
      }
      *(half4*)&sE[hidx] = mid;
      hacc[g] += m1;
    }
  }

  // agg1: butterfly over l31 spans all 128 j (4 jt x 32 lanes)
  #pragma unroll
  for (int m = 1; m < 32; m <<= 1)
    #pragma unroll
    for (int g = 0; g < 4; ++g)
      #pragma unroll
      for (int r = 0; r < 4; ++r)
        hacc[g][r] += __shfl_xor(hacc[g][r], m, 64);
  if (l31 == 0) {
    #pragma unroll
    for (int g = 0; g < 4; ++g)
      *(floatx4*)&agg1[(size_t)row * D + 32 * w + 8 * g + 4 * hl] = hacc[g];
  }

  // pass-2 weights (a1 dead -> regs reusable)
  half8 a2[8];
  #pragma unroll
  for (int ks = 0; ks < 8; ++ks)
    a2[ks] = *(const half8*)(weT2 + (32 * w + l31) * D + 16 * ks + 8 * hl);

  __syncthreads();                      // e_mid visible to all waves

  // --- pass 2: T2[c][j] = sum_k We2T[c][k] e_mid[j][k] ---
  #pragma unroll
  for (int jt = 0; jt < 4; ++jt) acc[jt] = vzero;
  #pragma unroll
  for (int ks = 0; ks < 8; ++ks)
    #pragma unroll
    for (int jt = 0; jt < 4; ++jt) {
      const half8 bv = *(const half8*)
          &sE[(32 * jt + l31) * D + (((2 * ks + hl) ^ l15) << 3)];
      acc[jt] = __builtin_amdgcn_mfma_f32_32x32x16_f16(a2[ks], bv, acc[jt], 0, 0, 0);
    }

  __syncthreads();                      // all pass-2 reads complete

  // --- deposit T2 into sE (same cell mapping) ---
  #pragma unroll
  for (int jt = 0; jt < 4; ++jt) {
    const int j = 32 * jt + l31;
    #pragma unroll
    for (int g = 0; g < 4; ++g) {
      const int hidx = j * D + (((4 * w + g) ^ l15) << 3) + 4 * hl;
      half4 tv;
      #pragma unroll
      for (int r = 0; r < 4; ++r) tv[r] = (_Float16)acc[jt][4 * g + r];
      *(half4*)&sE[hidx] = tv;
    }
  }

  __syncthreads();                      // T2 complete in LDS

  // --- coalesced copy-out (keeps swizzled global layout): 2048 uint4 ---
  uint4* gdst = (uint4*)(em + (size_t)row * N * D);
  const uint4* ls = (const uint4*)sE;
  #pragma unroll
  for (int u = 0; u < 8; ++u) {
    const int idx4 = u * 256 + t;
    gdst[idx4] = ls[idx4];
  }
}

// ---------------------------------------------------------------------------
// K6: final layer streaming: msg2 = relu(xi2 + xj2 + T2)*A; rowsum over j.
// T2 rows are cell-swizzled.
// ---------------------------------------------------------------------------
__global__ __launch_bounds__(256) void k_fin(
    const int* __restrict__ ei, const _Float16* __restrict__ t2,
    const float* __restrict__ xi, const float* __restrict__ xj,
    float* __restrict__ rowsum) {
  const int row = blockIdx.x;
  const int b = row >> 7;
  const int t = threadIdx.x;
  const int c8 = (t & 15) * 8, jr = t >> 4;

  __shared__ float sMask[N];
  __shared__ float hp[16][16][8];
  if (t < N) sMask[t] = (float)ei[(size_t)row * N + t];
  float xiv[8];
  *(floatx4*)&xiv[0] = *(const floatx4*)&xi[row * D + c8];
  *(floatx4*)&xiv[4] = *(const floatx4*)&xi[row * D + c8 + 4];
  __syncthreads();

  const _Float16* src = t2 + (size_t)row * N * D;
  const float* xjb = xj + (size_t)b * N * D;
  float acc8[8] = {};
  #pragma unroll
  for (int u = 0; u < 8; ++u) {
    const int j = u * 16 + jr;           // j&15 == jr
    const half8 tv = *(const half8*)(src + j * D + (((t & 15) ^ jr) << 3));
    const float am = sMask[j];
    const floatx4 xj0 = *(const floatx4*)&xjb[j * D + c8];
    const floatx4 xj1 = *(const floatx4*)&xjb[j * D + c8 + 4];
    #pragma unroll
    for (int r = 0; r < 4; ++r) {
      acc8[r]     += fmaxf(xiv[r] + xj0[r] + (float)tv[r], 0.f) * am;
      acc8[4 + r] += fmaxf(xiv[4 + r] + xj1[r] + (float)tv[4 + r], 0.f) * am;
    }
  }
  #pragma unroll
  for (int k = 0; k < 8; ++k) hp[jr][t & 15][k] = acc8[k];
  __syncthreads();
  if (t < D) {
    float s = 0.f;
    #pragma unroll
    for (int g = 0; g < 16; ++g) s += hp[g][t >> 3][t & 7];
    rowsum[row * D + t] = s;
  }
}

// ---------------------------------------------------------------------------
// K7: head MLP. 16 blocks.
// ---------------------------------------------------------------------------
__global__ __launch_bounds__(128) void k_head(
    const float* __restrict__ rowsum,
    const float* __restrict__ w1, const float* __restrict__ b1,
    const float* __restrict__ w2, const float* __restrict__ b2,
    const float* __restrict__ w3, const float* __restrict__ b3,
    float* __restrict__ out) {
  const int b = blockIdx.x;
  const int c = threadIdx.x;
  __shared__ float hr[D], h1r[D], h2r[D];
  const float* rs = rowsum + (size_t)b * N * D;
  float s = 0.f;
  for (int i = 0; i < N; ++i) s += rs[i * D + c];
  hr[c] = s * (1.f / (N * N));
  __syncthreads();
  float a = b1[c];
  #pragma unroll 8
  for (int k = 0; k < D; ++k) a = fmaf(hr[k], w1[k * D + c], a);
  h1r[c] = fmaxf(a, 0.f);
  __syncthreads();
  a = b2[c];
  #pragma unroll 8
  for (int k = 0; k < D; ++k) a = fmaf(h1r[k], w2[k * D + c], a);
  h2r[c] = fmaxf(a, 0.f);
  __syncthreads();
  hr[c] = h2r[c] * w3[c];
  __syncthreads();
  if (c == 0) {
    float s2 = b3[0];
    for (int k = 0; k < D; ++k) s2 += hr[k];
    out[b] = s2;
  }
}

// ---------------------------------------------------------------------------
extern "C" void kernel_launch(void* const* d_in, const int* in_sizes, int n_in,
                              void* d_out, int out_size, void* d_ws, size_t ws_size,
                              hipStream_t stream) {
  const int*   ei  = (const int*)d_in[0];
  const float* x0  = (const float*)d_in[1];
  const float* ea  = (const float*)d_in[2];
  const float* wm0 = (const float*)d_in[3];
  const float* bm0 = (const float*)d_in[4];
  const float* wn0 = (const float*)d_in[5];
  const float* bn0 = (const float*)d_in[6];
  const float* wm1 = (const float*)d_in[7];
  const float* bm1 = (const float*)d_in[8];
  const float* wn1 = (const float*)d_in[9];
  const float* bn1 = (const float*)d_in[10];
  const float* wm2 = (const float*)d_in[11];
  const float* bm2 = (const float*)d_in[12];
  const float* wh1 = (const float*)d_in[15];
  const float* bh1 = (const float*)d_in[16];
  const float* wh2 = (const float*)d_in[17];
  const float* bh2 = (const float*)d_in[18];
  const float* wh3 = (const float*)d_in[19];
  const float* bh3 = (const float*)d_in[20];
  float* out = (float*)d_out;

  _Float16* msg0h = (_Float16*)d_ws;                 // [B,N,N,D] fp16: msg0 -> T2
  _Float16* weT1  = msg0h + (size_t)B * N * N * D;
  _Float16* weT2  = weT1 + D * D;
  float* f = (float*)(weT2 + D * D);
  size_t off = 0;
  const size_t R = (size_t)B * N * D;
  float* xi0  = f + off; off += R;
  float* xj0  = f + off; off += R;
  float* agg0 = f + off; off += R;
  float* x1   = f + off; off += R;
  float* xi1  = f + off; off += R;
  float* xj1  = f + off; off += R;
  float* agg1 = f + off; off += R;
  float* xi2  = f + off; off += R;
  float* xj2  = f + off; off += R;
  float* rsum = f + off; off += R;

  const int rows = B * N;   // 2048
  k_wprep<<<256, 128, 0, stream>>>(wm1, wm2, weT1, weT2);
  k_pre0 <<<rows, 128, 0, stream>>>(x0, wm0, bm0, xi0, xj0);
  k_edge0<<<rows, 256, 0, stream>>>(ei, ea, wm0, xi0, xj0, msg0h, agg0);
  k_node0<<<rows, 128, 0, stream>>>(x0, agg0, wn0, bn0, wm1, bm1, x1, xi1, xj1);
  k_mid  <<<rows, 256, 0, stream>>>(ei, weT1, weT2, xi1, xj1, msg0h, agg1);
  k_node1<<<rows, 128, 0, stream>>>(x1, agg1, wn1, bn1, wm2, bm2, xi2, xj2);
  k_fin  <<<rows, 256, 0, stream>>>(ei, msg0h, xi2, xj2, rsum);
  k_head <<<B,    128, 0, stream>>>(rsum, wh1, bh1, wh2, bh2, wh3, bh3, out);
}